// Round 1
// 1506.092 us; speedup vs baseline: 4.0278x; 4.0278x over previous
//
#include <hip/hip_runtime.h>
#include <hip/hip_bf16.h>

#define T 2048
#define C 4096
#define H 32
#define KVH 8
#define D 128
// rep = H/KVH = 4

typedef __bf16 bf16x8 __attribute__((ext_vector_type(8)));
typedef __bf16 bf16x4 __attribute__((ext_vector_type(4)));
typedef float floatx4 __attribute__((ext_vector_type(4)));

// ---------------- split-bf16 MFMA GEMM ------------------------------------
// Cm[M][N] = A[M][K] @ B[K][N], fp32 in/out. Internally each operand is
// decomposed on the fly into hi+lo bf16; product = hh + lh + hl (drops the
// ~2^-18-relative lo*lo term). 128x128 tile, BK=32, 256 threads = 4 waves
// (2x2), each wave owns 64x64 = 4x4 frags of 16x16x32 MFMA (48 MFMA/k-step).
// LDS rows padded to 40 elems (80B): 16B-aligned for ds_read_b128, 20-bank
// rotation per row -> ~2-way conflicts (free).
__device__ __forceinline__ void gemm_split_body(
    const float* __restrict__ A, const float* __restrict__ B,
    float* __restrict__ Cm, int N, int K, int row0, int col0) {
  __shared__ __bf16 Ah[128][40], Al[128][40], Bh[128][40], Bl[128][40];
  const int tid = threadIdx.x;
  const int lane = tid & 63;
  const int w = tid >> 6;
  const int n16 = lane & 15;
  const int quad = lane >> 4;
  const int wm = w >> 1, wn = w & 1;

  floatx4 acc[4][4];
#pragma unroll
  for (int mi = 0; mi < 4; ++mi)
#pragma unroll
    for (int ni = 0; ni < 4; ++ni) acc[mi][ni] = (floatx4){0.f, 0.f, 0.f, 0.f};

  const int ar = tid >> 3;        // A row within 32-row group
  const int ak = (tid & 7) * 4;   // A k-quad (0,4,..,28)
  const int bg = tid >> 7;        // B k-group (0..1)
  const int bn = tid & 127;       // B col within tile

  for (int k0 = 0; k0 < K; k0 += 32) {
    // ---- stage A (128x32 fp32 -> hi/lo bf16, row-major [m][k]) ----
#pragma unroll
    for (int p = 0; p < 4; ++p) {
      const int r = p * 32 + ar;
      const float4 av = *(const float4*)(A + (size_t)(row0 + r) * K + k0 + ak);
      bf16x4 h, l;
      h[0] = (__bf16)av.x; l[0] = (__bf16)(av.x - (float)h[0]);
      h[1] = (__bf16)av.y; l[1] = (__bf16)(av.y - (float)h[1]);
      h[2] = (__bf16)av.z; l[2] = (__bf16)(av.z - (float)h[2]);
      h[3] = (__bf16)av.w; l[3] = (__bf16)(av.w - (float)h[3]);
      *(bf16x4*)(&Ah[r][ak]) = h;
      *(bf16x4*)(&Al[r][ak]) = l;
    }
    // ---- stage B (32x128 fp32 -> transposed LDS [n][k], hi/lo bf16) ----
#pragma unroll
    for (int p = 0; p < 4; ++p) {
      const int kb = bg * 16 + p * 4;
      const float* bp = B + (size_t)(k0 + kb) * N + col0 + bn;
      const float f0 = bp[0];
      const float f1 = bp[(size_t)N];
      const float f2 = bp[(size_t)2 * N];
      const float f3 = bp[(size_t)3 * N];
      bf16x4 h, l;
      h[0] = (__bf16)f0; l[0] = (__bf16)(f0 - (float)h[0]);
      h[1] = (__bf16)f1; l[1] = (__bf16)(f1 - (float)h[1]);
      h[2] = (__bf16)f2; l[2] = (__bf16)(f2 - (float)h[2]);
      h[3] = (__bf16)f3; l[3] = (__bf16)(f3 - (float)h[3]);
      *(bf16x4*)(&Bh[bn][kb]) = h;
      *(bf16x4*)(&Bl[bn][kb]) = l;
    }
    __syncthreads();
    // ---- fragments + 48 MFMAs ----
    bf16x8 a_h[4], a_l[4], b_h[4], b_l[4];
#pragma unroll
    for (int mi = 0; mi < 4; ++mi) {
      a_h[mi] = *(const bf16x8*)(&Ah[wm * 64 + mi * 16 + n16][quad * 8]);
      a_l[mi] = *(const bf16x8*)(&Al[wm * 64 + mi * 16 + n16][quad * 8]);
    }
#pragma unroll
    for (int ni = 0; ni < 4; ++ni) {
      b_h[ni] = *(const bf16x8*)(&Bh[wn * 64 + ni * 16 + n16][quad * 8]);
      b_l[ni] = *(const bf16x8*)(&Bl[wn * 64 + ni * 16 + n16][quad * 8]);
    }
#pragma unroll
    for (int mi = 0; mi < 4; ++mi)
#pragma unroll
      for (int ni = 0; ni < 4; ++ni) {
        acc[mi][ni] = __builtin_amdgcn_mfma_f32_16x16x32_bf16(a_h[mi], b_h[ni], acc[mi][ni], 0, 0, 0);
        acc[mi][ni] = __builtin_amdgcn_mfma_f32_16x16x32_bf16(a_l[mi], b_h[ni], acc[mi][ni], 0, 0, 0);
        acc[mi][ni] = __builtin_amdgcn_mfma_f32_16x16x32_bf16(a_h[mi], b_l[ni], acc[mi][ni], 0, 0, 0);
      }
    __syncthreads();
  }
  // ---- epilogue: C-layout row = quad*4+i, col = n16 ----
#pragma unroll
  for (int mi = 0; mi < 4; ++mi)
#pragma unroll
    for (int i = 0; i < 4; ++i) {
      const int r = row0 + wm * 64 + mi * 16 + quad * 4 + i;
      float* cp = Cm + (size_t)r * N + col0 + wn * 64 + n16;
#pragma unroll
      for (int ni = 0; ni < 4; ++ni) cp[ni * 16] = acc[mi][ni][i];
    }
}

__global__ __launch_bounds__(256) void gemm_split(
    const float* __restrict__ A, const float* __restrict__ B,
    float* __restrict__ Cm, int N, int K) {
  gemm_split_body(A, B, Cm, N, K, blockIdx.y * 128, blockIdx.x * 128);
}

// Wk and Wv projections fused into one 256-block launch (separately each is
// only 128 blocks = half the CUs idle).
__global__ __launch_bounds__(256) void gemm_kv(
    const float* __restrict__ A, const float* __restrict__ Bk,
    const float* __restrict__ Bv, float* __restrict__ Ck,
    float* __restrict__ Cv, int K) {
  const int bx = blockIdx.x;
  const float* Bp = (bx < 8) ? Bk : Bv;
  float* Cp = (bx < 8) ? Ck : Cv;
  gemm_split_body(A, Bp, Cp, KVH * D, K, blockIdx.y * 128, (bx & 7) * 128);
}

// ---------------- RoPE in-place on q (T x H*D) and k (T x KVH*D) ----------
__global__ __launch_bounds__(256) void rope_kernel(
    float* __restrict__ q, float* __restrict__ k,
    const float* __restrict__ cosb,
    const float* __restrict__ sinb) {
  int idx = blockIdx.x * 256 + threadIdx.x;
  int total = T * (H + KVH) * (D / 2);
  if (idx >= total) return;
  int d = idx % (D / 2);
  int rest = idx / (D / 2);
  int head = rest % (H + KVH);
  int t = rest / (H + KVH);
  float cv = cosb[(size_t)t * D + d];
  float sv = sinb[(size_t)t * D + d];
  float* base;
  if (head < H) base = q + (size_t)t * (H * D) + head * D;
  else          base = k + (size_t)t * (KVH * D) + (head - H) * D;
  float u1 = base[d];
  float u2 = base[d + D / 2];
  base[d]         = u1 * cv - u2 * sv;
  base[d + D / 2] = u2 * cv + u1 * sv;
}

// ---- k: emit out_k (fp32 [kvh][t][d]) + khi/klo (bf16 split, same layout) ----
__global__ __launch_bounds__(256) void convert_k(
    const float* __restrict__ k_ws, float* __restrict__ out_k,
    __bf16* __restrict__ khi, __bf16* __restrict__ klo) {
  int idx = blockIdx.x * 256 + threadIdx.x;
  if (idx >= KVH * T * D) return;
  int d = idx & (D - 1);
  int t = (idx >> 7) & (T - 1);
  int kvh = idx >> 18;
  float f = k_ws[(size_t)t * (KVH * D) + kvh * D + d];
  out_k[idx] = f;                      // idx == ((kvh*T)+t)*D + d
  __bf16 hi = (__bf16)f;
  khi[idx] = hi;
  klo[idx] = (__bf16)(f - (float)hi);
}

// ---- v: emit out_v (fp32 [kvh][t][d]) + vt (bf16 transposed [kvh][d][t]) ----
__global__ __launch_bounds__(256) void convert_v(
    const float* __restrict__ v_ws, float* __restrict__ out_v,
    __bf16* __restrict__ vt) {
  __shared__ __bf16 tile[64][65];
  const int t0 = blockIdx.x * 64;
  const int d0 = blockIdx.y * 64;
  const int kvh = blockIdx.z;
#pragma unroll
  for (int p = 0; p < 16; ++p) {
    int i = p * 256 + threadIdx.x;
    int r = i >> 6;      // t offset
    int c = i & 63;      // d offset (consecutive tid -> coalesced)
    float f = v_ws[(size_t)(t0 + r) * (KVH * D) + kvh * D + d0 + c];
    out_v[((size_t)kvh * T + t0 + r) * D + d0 + c] = f;
    tile[r][c] = (__bf16)f;
  }
  __syncthreads();
#pragma unroll
  for (int p = 0; p < 16; ++p) {
    int i = p * 256 + threadIdx.x;
    int dd = i >> 6;     // d offset
    int tt = i & 63;     // t offset (consecutive tid -> coalesced)
    vt[((size_t)kvh * D + d0 + dd) * T + t0 + tt] = tile[tt][dd];
  }
}

// ---------------- MFMA flash attention, barrier-free -----------------------
// Grid (T/64, H); 256 threads = 4 independent waves; wave w owns q rows
// [bx*64 + w*16, +16) of head h. Split-precision bf16 QK^T (3 MFMAs / chunk),
// plain bf16 PV. Online softmax in registers; P goes C-layout -> A-layout via
// a per-wave LDS round-trip (DS ops are in-order per wave; no barrier).
// Masked cols use -inf; every processed tile has >=1 valid col per row since
// j0 <= r_base always. Output overwrites q in place (wave reads exactly the
// q elements it later writes; no cross-wave overlap).
__global__ __launch_bounds__(256) void flash_attn(
    float* __restrict__ q,
    const __bf16* __restrict__ khi,   // [KVH][T][D]
    const __bf16* __restrict__ klo,   // [KVH][T][D]
    const __bf16* __restrict__ vt) {  // [KVH][D][T]
  __shared__ __attribute__((aligned(16))) __bf16 Pst[4][16][40];
  const int tid = threadIdx.x;
  const int w = tid >> 6;
  const int lane = tid & 63;
  const int n16 = lane & 15;
  const int quad = lane >> 4;
  const int h = blockIdx.y;
  const int kvh = h >> 2;
  const int r_base = blockIdx.x * 64 + w * 16;

  // Q fragments, A-layout: lane holds row m = n16, k-dim d = c*32 + quad*8 + jj
  bf16x8 qhi[4], qlo[4];
  {
    const float* qrow = q + (size_t)(r_base + n16) * C + h * D;
#pragma unroll
    for (int c = 0; c < 4; ++c) {
      const float* p = qrow + c * 32 + quad * 8;
#pragma unroll
      for (int jj = 0; jj < 8; ++jj) {
        float f = p[jj];
        __bf16 hi = (__bf16)f;
        qhi[c][jj] = hi;
        qlo[c][jj] = (__bf16)(f - (float)hi);
      }
    }
  }

  floatx4 O[8];
#pragma unroll
  for (int dt = 0; dt < 8; ++dt) O[dt] = (floatx4){0.f, 0.f, 0.f, 0.f};
  float m_i[4] = {-INFINITY, -INFINITY, -INFINITY, -INFINITY};
  float l_i[4] = {0.f, 0.f, 0.f, 0.f};

  const __bf16* Kh = khi + (size_t)kvh * T * D;
  const __bf16* Kl = klo + (size_t)kvh * T * D;
  const __bf16* Vt = vt + (size_t)kvh * D * T;

  const int ntiles = (r_base + 15) / 32 + 1;
  for (int t = 0; t < ntiles; ++t) {
    const int j0 = t * 32;
    floatx4 s0 = {0.f, 0.f, 0.f, 0.f};
    floatx4 s1 = {0.f, 0.f, 0.f, 0.f};
#pragma unroll
    for (int c = 0; c < 4; ++c) {
      const size_t off = (size_t)c * 32 + quad * 8;
      bf16x8 k0h = *(const bf16x8*)(Kh + (size_t)(j0 + n16) * D + off);
      bf16x8 k0l = *(const bf16x8*)(Kl + (size_t)(j0 + n16) * D + off);
      bf16x8 k1h = *(const bf16x8*)(Kh + (size_t)(j0 + 16 + n16) * D + off);
      bf16x8 k1l = *(const bf16x8*)(Kl + (size_t)(j0 + 16 + n16) * D + off);
      s0 = __builtin_amdgcn_mfma_f32_16x16x32_bf16(qhi[c], k0h, s0, 0, 0, 0);
      s0 = __builtin_amdgcn_mfma_f32_16x16x32_bf16(qlo[c], k0h, s0, 0, 0, 0);
      s0 = __builtin_amdgcn_mfma_f32_16x16x32_bf16(qhi[c], k0l, s0, 0, 0, 0);
      s1 = __builtin_amdgcn_mfma_f32_16x16x32_bf16(qhi[c], k1h, s1, 0, 0, 0);
      s1 = __builtin_amdgcn_mfma_f32_16x16x32_bf16(qlo[c], k1h, s1, 0, 0, 0);
      s1 = __builtin_amdgcn_mfma_f32_16x16x32_bf16(qhi[c], k1l, s1, 0, 0, 0);
    }
    // causal mask (wave-uniform branch; C-layout rows r = r_base + quad*4 + i)
    if (j0 + 31 > r_base) {
#pragma unroll
      for (int i = 0; i < 4; ++i) {
        int r = r_base + quad * 4 + i;
        if (j0 + n16 > r) s0[i] = -INFINITY;
        if (j0 + 16 + n16 > r) s1[i] = -INFINITY;
      }
    }
    // online softmax, per C-layout row
    float p0[4], p1[4];
#pragma unroll
    for (int i = 0; i < 4; ++i) {
      float mt = fmaxf(s0[i], s1[i]);
      mt = fmaxf(mt, __shfl_xor(mt, 1));
      mt = fmaxf(mt, __shfl_xor(mt, 2));
      mt = fmaxf(mt, __shfl_xor(mt, 4));
      mt = fmaxf(mt, __shfl_xor(mt, 8));
      float mn = fmaxf(m_i[i], mt);
      float alpha = __expf(m_i[i] - mn);   // first tile: exp(-inf)=0
      m_i[i] = mn;
      p0[i] = __expf(s0[i] - mn);
      p1[i] = __expf(s1[i] - mn);
      float rs = p0[i] + p1[i];
      rs += __shfl_xor(rs, 1);
      rs += __shfl_xor(rs, 2);
      rs += __shfl_xor(rs, 4);
      rs += __shfl_xor(rs, 8);
      l_i[i] = l_i[i] * alpha + rs;
#pragma unroll
      for (int dt = 0; dt < 8; ++dt) O[dt][i] *= alpha;
    }
    // P: C-layout -> A-layout via per-wave LDS round-trip (no barrier needed)
#pragma unroll
    for (int i = 0; i < 4; ++i) {
      Pst[w][quad * 4 + i][n16] = (__bf16)p0[i];
      Pst[w][quad * 4 + i][n16 + 16] = (__bf16)p1[i];
    }
    bf16x8 pA = *(const bf16x8*)(&Pst[w][n16][quad * 8]);
    // PV: B = V, lane holds d = dt*16 + n16, keys quad*8 + jj
    const __bf16* vb = Vt + j0 + quad * 8;
#pragma unroll
    for (int dt = 0; dt < 8; ++dt) {
      bf16x8 vB = *(const bf16x8*)(vb + (size_t)(dt * 16 + n16) * T);
      O[dt] = __builtin_amdgcn_mfma_f32_16x16x32_bf16(pA, vB, O[dt], 0, 0, 0);
    }
  }
  // epilogue: y = O / l, overwrite q rows in place
#pragma unroll
  for (int i = 0; i < 4; ++i) {
    float inv = 1.0f / l_i[i];
    int r = r_base + quad * 4 + i;
    float* yp = q + (size_t)r * C + h * D + n16;
#pragma unroll
    for (int dt = 0; dt < 8; ++dt) yp[dt * 16] = O[dt][i] * inv;
  }
}

extern "C" void kernel_launch(void* const* d_in, const int* in_sizes, int n_in,
                              void* d_out, int out_size, void* d_ws, size_t ws_size,
                              hipStream_t stream) {
  (void)in_sizes; (void)n_in; (void)out_size; (void)ws_size;
  const float* x    = (const float*)d_in[0];
  const float* Wq   = (const float*)d_in[1];
  const float* Wk   = (const float*)d_in[2];
  const float* Wv   = (const float*)d_in[3];
  const float* Wo   = (const float*)d_in[4];
  const float* cosb = (const float*)d_in[5];
  const float* sinb = (const float*)d_in[6];
  // d_in[7] = mask: unused (causal structure applied exactly)

  // workspace layout (~60 MB)
  float* q_ws = (float*)d_ws;                         // T*C fp32 (q, then y in-place)
  float* k_ws = q_ws + (size_t)T * C;                 // T*KVH*D fp32
  float* v_ws = k_ws + (size_t)T * KVH * D;           // T*KVH*D fp32
  __bf16* khi = (__bf16*)(v_ws + (size_t)T * KVH * D);          // 4 MB
  __bf16* klo = khi + (size_t)KVH * T * D;                      // 4 MB
  __bf16* vt  = klo + (size_t)KVH * T * D;                      // 4 MB

  float* out_y = (float*)d_out;
  float* out_k = out_y + (size_t)T * C;
  float* out_v = out_k + (size_t)KVH * T * D;

  dim3 blk(256);
  // projections: split-bf16 MFMA GEMMs
  gemm_split<<<dim3(C / 128, T / 128), blk, 0, stream>>>(x, Wq, q_ws, H * D, C);
  gemm_kv<<<dim3(16, T / 128), blk, 0, stream>>>(x, Wk, Wv, k_ws, v_ws, C);
  // rope on q and k (in place)
  int rope_total = T * (H + KVH) * (D / 2);
  rope_kernel<<<(rope_total + 255) / 256, blk, 0, stream>>>(q_ws, k_ws, cosb, sinb);
  // conversions + kv outputs
  convert_k<<<(KVH * T * D) / 256, blk, 0, stream>>>(k_ws, out_k, khi, klo);
  convert_v<<<dim3(T / 64, D / 64, KVH), blk, 0, stream>>>(v_ws, out_v, vt);
  // flash attention (writes y over q_ws)
  flash_attn<<<dim3(T / 64, H), blk, 0, stream>>>(q_ws, khi, klo, vt);
  // output projection
  gemm_split<<<dim3(C / 128, T / 128), blk, 0, stream>>>(q_ws, Wo, out_y, C, C);
}

// Round 2
// 957.199 us; speedup vs baseline: 6.3375x; 1.5734x over previous
//
#include <hip/hip_runtime.h>
#include <hip/hip_bf16.h>

#define T 2048
#define C 4096
#define H 32
#define KVH 8
#define D 128
// rep = H/KVH = 4

typedef __bf16 bf16x8 __attribute__((ext_vector_type(8)));
typedef __bf16 bf16x4 __attribute__((ext_vector_type(4)));
typedef float floatx4 __attribute__((ext_vector_type(4)));

#define MFMA16 __builtin_amdgcn_mfma_f32_16x16x32_bf16

// ---------------- split-bf16 MFMA GEMM ------------------------------------
// Cm[M][N] = A[M][K] @ B[K][N], fp32 in/out. Internally each operand is
// decomposed on the fly into hi+lo bf16; product = hh + lh + hl (drops the
// ~2^-18-relative lo*lo term). 128x128 tile, BK=32, 256 threads = 4 waves
// (2x2), each wave owns 64x64 = 4x4 frags of 16x16x32 MFMA (48 MFMA/k-step).
__device__ __forceinline__ void gemm_split_body(
    const float* __restrict__ A, const float* __restrict__ B,
    float* __restrict__ Cm, int N, int K, int row0, int col0) {
  __shared__ __bf16 Ah[128][40], Al[128][40], Bh[128][40], Bl[128][40];
  const int tid = threadIdx.x;
  const int lane = tid & 63;
  const int w = tid >> 6;
  const int n16 = lane & 15;
  const int quad = lane >> 4;
  const int wm = w >> 1, wn = w & 1;

  floatx4 acc[4][4];
#pragma unroll
  for (int mi = 0; mi < 4; ++mi)
#pragma unroll
    for (int ni = 0; ni < 4; ++ni) acc[mi][ni] = (floatx4){0.f, 0.f, 0.f, 0.f};

  const int ar = tid >> 3;        // A row within 32-row group
  const int ak = (tid & 7) * 4;   // A k-quad (0,4,..,28)
  const int bg = tid >> 7;        // B k-group (0..1)
  const int bn = tid & 127;       // B col within tile

  for (int k0 = 0; k0 < K; k0 += 32) {
    // ---- stage A (128x32 fp32 -> hi/lo bf16, row-major [m][k]) ----
#pragma unroll
    for (int p = 0; p < 4; ++p) {
      const int r = p * 32 + ar;
      const float4 av = *(const float4*)(A + (size_t)(row0 + r) * K + k0 + ak);
      bf16x4 h, l;
      h[0] = (__bf16)av.x; l[0] = (__bf16)(av.x - (float)h[0]);
      h[1] = (__bf16)av.y; l[1] = (__bf16)(av.y - (float)h[1]);
      h[2] = (__bf16)av.z; l[2] = (__bf16)(av.z - (float)h[2]);
      h[3] = (__bf16)av.w; l[3] = (__bf16)(av.w - (float)h[3]);
      *(bf16x4*)(&Ah[r][ak]) = h;
      *(bf16x4*)(&Al[r][ak]) = l;
    }
    // ---- stage B (32x128 fp32 -> transposed LDS [n][k], hi/lo bf16) ----
#pragma unroll
    for (int p = 0; p < 4; ++p) {
      const int kb = bg * 16 + p * 4;
      const float* bp = B + (size_t)(k0 + kb) * N + col0 + bn;
      const float f0 = bp[0];
      const float f1 = bp[(size_t)N];
      const float f2 = bp[(size_t)2 * N];
      const float f3 = bp[(size_t)3 * N];
      bf16x4 h, l;
      h[0] = (__bf16)f0; l[0] = (__bf16)(f0 - (float)h[0]);
      h[1] = (__bf16)f1; l[1] = (__bf16)(f1 - (float)h[1]);
      h[2] = (__bf16)f2; l[2] = (__bf16)(f2 - (float)h[2]);
      h[3] = (__bf16)f3; l[3] = (__bf16)(f3 - (float)h[3]);
      *(bf16x4*)(&Bh[bn][kb]) = h;
      *(bf16x4*)(&Bl[bn][kb]) = l;
    }
    __syncthreads();
    // ---- fragments + 48 MFMAs ----
    bf16x8 a_h[4], a_l[4], b_h[4], b_l[4];
#pragma unroll
    for (int mi = 0; mi < 4; ++mi) {
      a_h[mi] = *(const bf16x8*)(&Ah[wm * 64 + mi * 16 + n16][quad * 8]);
      a_l[mi] = *(const bf16x8*)(&Al[wm * 64 + mi * 16 + n16][quad * 8]);
    }
#pragma unroll
    for (int ni = 0; ni < 4; ++ni) {
      b_h[ni] = *(const bf16x8*)(&Bh[wn * 64 + ni * 16 + n16][quad * 8]);
      b_l[ni] = *(const bf16x8*)(&Bl[wn * 64 + ni * 16 + n16][quad * 8]);
    }
#pragma unroll
    for (int mi = 0; mi < 4; ++mi)
#pragma unroll
      for (int ni = 0; ni < 4; ++ni) {
        acc[mi][ni] = MFMA16(a_h[mi], b_h[ni], acc[mi][ni], 0, 0, 0);
        acc[mi][ni] = MFMA16(a_l[mi], b_h[ni], acc[mi][ni], 0, 0, 0);
        acc[mi][ni] = MFMA16(a_h[mi], b_l[ni], acc[mi][ni], 0, 0, 0);
      }
    __syncthreads();
  }
  // ---- epilogue: C-layout row = quad*4+i, col = n16 ----
#pragma unroll
  for (int mi = 0; mi < 4; ++mi)
#pragma unroll
    for (int i = 0; i < 4; ++i) {
      const int r = row0 + wm * 64 + mi * 16 + quad * 4 + i;
      float* cp = Cm + (size_t)r * N + col0 + wn * 64 + n16;
#pragma unroll
      for (int ni = 0; ni < 4; ++ni) cp[ni * 16] = acc[mi][ni][i];
    }
}

__global__ __launch_bounds__(256) void gemm_split(
    const float* __restrict__ A, const float* __restrict__ B,
    float* __restrict__ Cm, int N, int K) {
  gemm_split_body(A, B, Cm, N, K, blockIdx.y * 128, blockIdx.x * 128);
}

// Wk and Wv projections fused into one 256-block launch.
__global__ __launch_bounds__(256) void gemm_kv(
    const float* __restrict__ A, const float* __restrict__ Bk,
    const float* __restrict__ Bv, float* __restrict__ Ck,
    float* __restrict__ Cv, int K) {
  const int bx = blockIdx.x;
  const float* Bp = (bx < 8) ? Bk : Bv;
  float* Cp = (bx < 8) ? Ck : Cv;
  gemm_split_body(A, Bp, Cp, KVH * D, K, blockIdx.y * 128, (bx & 7) * 128);
}

// ---------------- RoPE in-place on q (T x H*D) and k (T x KVH*D) ----------
__global__ __launch_bounds__(256) void rope_kernel(
    float* __restrict__ q, float* __restrict__ k,
    const float* __restrict__ cosb,
    const float* __restrict__ sinb) {
  int idx = blockIdx.x * 256 + threadIdx.x;
  int total = T * (H + KVH) * (D / 2);
  if (idx >= total) return;
  int d = idx % (D / 2);
  int rest = idx / (D / 2);
  int head = rest % (H + KVH);
  int t = rest / (H + KVH);
  float cv = cosb[(size_t)t * D + d];
  float sv = sinb[(size_t)t * D + d];
  float* base;
  if (head < H) base = q + (size_t)t * (H * D) + head * D;
  else          base = k + (size_t)t * (KVH * D) + (head - H) * D;
  float u1 = base[d];
  float u2 = base[d + D / 2];
  base[d]         = u1 * cv - u2 * sv;
  base[d + D / 2] = u2 * cv + u1 * sv;
}

// ---- k: emit out_k (fp32 [kvh][t][d]) + khi/klo (bf16 split, same layout) ----
__global__ __launch_bounds__(256) void convert_k(
    const float* __restrict__ k_ws, float* __restrict__ out_k,
    __bf16* __restrict__ khi, __bf16* __restrict__ klo) {
  int idx = blockIdx.x * 256 + threadIdx.x;
  if (idx >= KVH * T * D) return;
  int d = idx & (D - 1);
  int t = (idx >> 7) & (T - 1);
  int kvh = idx >> 18;
  float f = k_ws[(size_t)t * (KVH * D) + kvh * D + d];
  out_k[idx] = f;                      // idx == ((kvh*T)+t)*D + d
  __bf16 hi = (__bf16)f;
  khi[idx] = hi;
  klo[idx] = (__bf16)(f - (float)hi);
}

// ---- v: emit out_v (fp32 [kvh][t][d]) + vt (bf16 transposed [kvh][d][t]) ----
__global__ __launch_bounds__(256) void convert_v(
    const float* __restrict__ v_ws, float* __restrict__ out_v,
    __bf16* __restrict__ vt) {
  __shared__ __bf16 tile[64][65];
  const int t0 = blockIdx.x * 64;
  const int d0 = blockIdx.y * 64;
  const int kvh = blockIdx.z;
#pragma unroll
  for (int p = 0; p < 16; ++p) {
    int i = p * 256 + threadIdx.x;
    int r = i >> 6;      // t offset
    int c = i & 63;      // d offset (consecutive tid -> coalesced)
    float f = v_ws[(size_t)(t0 + r) * (KVH * D) + kvh * D + d0 + c];
    out_v[((size_t)kvh * T + t0 + r) * D + d0 + c] = f;
    tile[r][c] = (__bf16)f;
  }
  __syncthreads();
#pragma unroll
  for (int p = 0; p < 16; ++p) {
    int i = p * 256 + threadIdx.x;
    int dd = i >> 6;     // d offset
    int tt = i & 63;     // t offset (consecutive tid -> coalesced)
    vt[((size_t)kvh * D + d0 + dd) * T + t0 + tt] = tile[tt][dd];
  }
}

// ---------------- MFMA flash attention, balanced + LDS-staged --------------
// Grid (T/128, H); block bx owns Q-blocks p_lo=bx and p_hi=31-bx (light+heavy
// pairing -> uniform per-block compute). 4 waves; wave w owns 16-row strips
// of BOTH Q-blocks. Per KV step the whole block cooperatively stages K(hi+lo)
// and V tiles into double-buffered LDS (T3-lite 2-phase: issue loads for t+1
// before compute of t, ds_write after, ONE barrier per tile). K-frags and V
// tile shared between the two strips. LDS strides: K 136 elem (272B), V/P 40
// elem (80B) -> all ds_read_b128 patterns 2-way bank aliasing (free).
struct StageRegs { bf16x8 k0, k1, l0, l1, v0, v1; };

__device__ __forceinline__ void stage_load(
    StageRegs& s, const __bf16* __restrict__ Kh, const __bf16* __restrict__ Kl,
    const __bf16* __restrict__ Vt, int j0, int tid) {
  const int kr = tid >> 4, kj = (tid & 15) * 8;
  s.k0 = *(const bf16x8*)(Kh + (size_t)(j0 + kr) * D + kj);
  s.k1 = *(const bf16x8*)(Kh + (size_t)(j0 + kr + 16) * D + kj);
  s.l0 = *(const bf16x8*)(Kl + (size_t)(j0 + kr) * D + kj);
  s.l1 = *(const bf16x8*)(Kl + (size_t)(j0 + kr + 16) * D + kj);
  const int vd = tid >> 2, vj = (tid & 3) * 8;
  s.v0 = *(const bf16x8*)(Vt + (size_t)vd * T + j0 + vj);
  s.v1 = *(const bf16x8*)(Vt + (size_t)(vd + 64) * T + j0 + vj);
}

__device__ __forceinline__ void stage_write(
    const StageRegs& s, __bf16* __restrict__ KhL, __bf16* __restrict__ KlL,
    __bf16* __restrict__ VL, int tid) {
  const int kr = tid >> 4, kj = (tid & 15) * 8;
  *(bf16x8*)(KhL + kr * 136 + kj) = s.k0;
  *(bf16x8*)(KhL + (kr + 16) * 136 + kj) = s.k1;
  *(bf16x8*)(KlL + kr * 136 + kj) = s.l0;
  *(bf16x8*)(KlL + (kr + 16) * 136 + kj) = s.l1;
  const int vd = tid >> 2, vj = (tid & 3) * 8;
  *(bf16x8*)(VL + vd * 40 + vj) = s.v0;
  *(bf16x8*)(VL + (vd + 64) * 40 + vj) = s.v1;
}

__device__ __forceinline__ void softmax_pv(
    floatx4 s0, floatx4 s1,
    const __bf16* __restrict__ VT, __bf16* __restrict__ Pw,
    floatx4* __restrict__ O, float* __restrict__ m_i, float* __restrict__ l_i,
    int j0, int r_base, int n16, int quad) {
  // causal mask (wave-uniform branch; C-layout rows r = r_base + quad*4 + i)
  if (j0 + 31 > r_base) {
#pragma unroll
    for (int i = 0; i < 4; ++i) {
      int r = r_base + quad * 4 + i;
      if (j0 + n16 > r) s0[i] = -INFINITY;
      if (j0 + 16 + n16 > r) s1[i] = -INFINITY;
    }
  }
  float p0[4], p1[4];
#pragma unroll
  for (int i = 0; i < 4; ++i) {
    float mt = fmaxf(s0[i], s1[i]);
    mt = fmaxf(mt, __shfl_xor(mt, 1));
    mt = fmaxf(mt, __shfl_xor(mt, 2));
    mt = fmaxf(mt, __shfl_xor(mt, 4));
    mt = fmaxf(mt, __shfl_xor(mt, 8));
    float mn = fmaxf(m_i[i], mt);
    float alpha = __expf(m_i[i] - mn);   // first tile: exp(-inf)=0
    m_i[i] = mn;
    p0[i] = __expf(s0[i] - mn);
    p1[i] = __expf(s1[i] - mn);
    float rs = p0[i] + p1[i];
    rs += __shfl_xor(rs, 1);
    rs += __shfl_xor(rs, 2);
    rs += __shfl_xor(rs, 4);
    rs += __shfl_xor(rs, 8);
    l_i[i] = l_i[i] * alpha + rs;
#pragma unroll
    for (int dt = 0; dt < 8; ++dt) O[dt][i] *= alpha;
  }
  // P: C-layout -> A-layout via per-wave LDS round-trip (no barrier needed)
#pragma unroll
  for (int i = 0; i < 4; ++i) {
    Pw[(quad * 4 + i) * 40 + n16] = (__bf16)p0[i];
    Pw[(quad * 4 + i) * 40 + n16 + 16] = (__bf16)p1[i];
  }
  bf16x8 pA = *(const bf16x8*)(Pw + n16 * 40 + quad * 8);
#pragma unroll
  for (int dt = 0; dt < 8; ++dt) {
    bf16x8 vB = *(const bf16x8*)(VT + (dt * 16 + n16) * 40 + quad * 8);
    O[dt] = MFMA16(pA, vB, O[dt], 0, 0, 0);
  }
}

template <bool BOTH>
__device__ __forceinline__ void attn_tile2(
    const __bf16* __restrict__ KhT, const __bf16* __restrict__ KlT,
    const __bf16* __restrict__ VT, __bf16* __restrict__ Pw,
    const bf16x8* qh_hi, const bf16x8* ql_hi,
    const bf16x8* qh_lo, const bf16x8* ql_lo,
    floatx4* O_hi, float* m_hi, float* l_hi,
    floatx4* O_lo, float* m_lo, float* l_lo,
    int j0, int rb_hi, int rb_lo, int n16, int quad) {
  floatx4 sh0 = {0.f, 0.f, 0.f, 0.f}, sh1 = {0.f, 0.f, 0.f, 0.f};
  floatx4 sl0 = {0.f, 0.f, 0.f, 0.f}, sl1 = {0.f, 0.f, 0.f, 0.f};
#pragma unroll
  for (int c = 0; c < 4; ++c) {
    const int off = c * 32 + quad * 8;
    bf16x8 k0h = *(const bf16x8*)(KhT + n16 * 136 + off);
    bf16x8 k1h = *(const bf16x8*)(KhT + (n16 + 16) * 136 + off);
    bf16x8 k0l = *(const bf16x8*)(KlT + n16 * 136 + off);
    bf16x8 k1l = *(const bf16x8*)(KlT + (n16 + 16) * 136 + off);
    sh0 = MFMA16(qh_hi[c], k0h, sh0, 0, 0, 0);
    sh0 = MFMA16(ql_hi[c], k0h, sh0, 0, 0, 0);
    sh0 = MFMA16(qh_hi[c], k0l, sh0, 0, 0, 0);
    sh1 = MFMA16(qh_hi[c], k1h, sh1, 0, 0, 0);
    sh1 = MFMA16(ql_hi[c], k1h, sh1, 0, 0, 0);
    sh1 = MFMA16(qh_hi[c], k1l, sh1, 0, 0, 0);
    if (BOTH) {
      sl0 = MFMA16(qh_lo[c], k0h, sl0, 0, 0, 0);
      sl0 = MFMA16(ql_lo[c], k0h, sl0, 0, 0, 0);
      sl0 = MFMA16(qh_lo[c], k0l, sl0, 0, 0, 0);
      sl1 = MFMA16(qh_lo[c], k1h, sl1, 0, 0, 0);
      sl1 = MFMA16(ql_lo[c], k1h, sl1, 0, 0, 0);
      sl1 = MFMA16(qh_lo[c], k1l, sl1, 0, 0, 0);
    }
  }
  softmax_pv(sh0, sh1, VT, Pw, O_hi, m_hi, l_hi, j0, rb_hi, n16, quad);
  if (BOTH) softmax_pv(sl0, sl1, VT, Pw, O_lo, m_lo, l_lo, j0, rb_lo, n16, quad);
}

__global__ __launch_bounds__(256, 2) void flash_attn(
    float* __restrict__ q,
    const __bf16* __restrict__ khi,   // [KVH][T][D]
    const __bf16* __restrict__ klo,   // [KVH][T][D]
    const __bf16* __restrict__ vt) {  // [KVH][D][T]
  __shared__ __attribute__((aligned(16))) __bf16 KhL[2][32 * 136];
  __shared__ __attribute__((aligned(16))) __bf16 KlL[2][32 * 136];
  __shared__ __attribute__((aligned(16))) __bf16 VL[2][128 * 40];
  __shared__ __attribute__((aligned(16))) __bf16 Pst[4][16 * 40];

  const int tid = threadIdx.x;
  const int w = tid >> 6;
  const int lane = tid & 63;
  const int n16 = lane & 15;
  const int quad = lane >> 4;
  const int h = blockIdx.y;
  const int kvh = h >> 2;
  const int p_lo = blockIdx.x;         // 0..15
  const int p_hi = 31 - p_lo;          // 16..31
  const int rb_lo = p_lo * 64 + w * 16;
  const int rb_hi = p_hi * 64 + w * 16;
  const int nt = 64 - 2 * p_lo;              // block-uniform loop count
  const int nt_lo = (rb_lo + 15) / 32 + 1;   // wave-uniform strip bounds
  const int nt_hi = (rb_hi + 15) / 32 + 1;

  const __bf16* Kh = khi + (size_t)kvh * T * D;
  const __bf16* Kl = klo + (size_t)kvh * T * D;
  const __bf16* Vt = vt + (size_t)kvh * D * T;

  // Q fragments (both strips), A-layout: row m = n16, k = c*32 + quad*8 + jj
  bf16x8 qh_lo[4], ql_lo[4], qh_hi[4], ql_hi[4];
  {
    const float* qr_lo = q + (size_t)(rb_lo + n16) * C + h * D;
    const float* qr_hi = q + (size_t)(rb_hi + n16) * C + h * D;
#pragma unroll
    for (int c = 0; c < 4; ++c) {
      const float4 a0 = *(const float4*)(qr_lo + c * 32 + quad * 8);
      const float4 a1 = *(const float4*)(qr_lo + c * 32 + quad * 8 + 4);
      const float4 b0 = *(const float4*)(qr_hi + c * 32 + quad * 8);
      const float4 b1 = *(const float4*)(qr_hi + c * 32 + quad * 8 + 4);
      const float fl[8] = {a0.x, a0.y, a0.z, a0.w, a1.x, a1.y, a1.z, a1.w};
      const float fh[8] = {b0.x, b0.y, b0.z, b0.w, b1.x, b1.y, b1.z, b1.w};
#pragma unroll
      for (int jj = 0; jj < 8; ++jj) {
        __bf16 hl = (__bf16)fl[jj];
        qh_lo[c][jj] = hl;
        ql_lo[c][jj] = (__bf16)(fl[jj] - (float)hl);
        __bf16 hh = (__bf16)fh[jj];
        qh_hi[c][jj] = hh;
        ql_hi[c][jj] = (__bf16)(fh[jj] - (float)hh);
      }
    }
  }

  floatx4 O_lo[8], O_hi[8];
#pragma unroll
  for (int dt = 0; dt < 8; ++dt) {
    O_lo[dt] = (floatx4){0.f, 0.f, 0.f, 0.f};
    O_hi[dt] = (floatx4){0.f, 0.f, 0.f, 0.f};
  }
  float m_lo[4] = {-INFINITY, -INFINITY, -INFINITY, -INFINITY};
  float m_hi[4] = {-INFINITY, -INFINITY, -INFINITY, -INFINITY};
  float l_lo[4] = {0.f, 0.f, 0.f, 0.f};
  float l_hi[4] = {0.f, 0.f, 0.f, 0.f};

  // prologue: stage tile 0 into buffer 0
  StageRegs sreg;
  stage_load(sreg, Kh, Kl, Vt, 0, tid);
  stage_write(sreg, KhL[0], KlL[0], VL[0], tid);
  __syncthreads();

  __bf16* Pw = Pst[w];
  for (int t = 0; t < nt; ++t) {
    const int cur = t & 1;
    const int j0 = t * 32;
    if (t + 1 < nt) stage_load(sreg, Kh, Kl, Vt, j0 + 32, tid);   // issue early
    if (t < nt_hi) {                                              // wave-uniform
      if (t < nt_lo)
        attn_tile2<true>(KhL[cur], KlL[cur], VL[cur], Pw,
                         qh_hi, ql_hi, qh_lo, ql_lo,
                         O_hi, m_hi, l_hi, O_lo, m_lo, l_lo,
                         j0, rb_hi, rb_lo, n16, quad);
      else
        attn_tile2<false>(KhL[cur], KlL[cur], VL[cur], Pw,
                          qh_hi, ql_hi, qh_lo, ql_lo,
                          O_hi, m_hi, l_hi, O_lo, m_lo, l_lo,
                          j0, rb_hi, rb_lo, n16, quad);
    }
    if (t + 1 < nt) stage_write(sreg, KhL[cur ^ 1], KlL[cur ^ 1], VL[cur ^ 1], tid);
    __syncthreads();   // writes visible before next compute; readers of cur done
  }

  // epilogue: y = O / l, overwrite q rows in place (both strips)
#pragma unroll
  for (int i = 0; i < 4; ++i) {
    float inv_l = 1.0f / l_lo[i];
    float inv_h = 1.0f / l_hi[i];
    int r_l = rb_lo + quad * 4 + i;
    int r_h = rb_hi + quad * 4 + i;
    float* yl = q + (size_t)r_l * C + h * D + n16;
    float* yh = q + (size_t)r_h * C + h * D + n16;
#pragma unroll
    for (int dt = 0; dt < 8; ++dt) {
      yl[dt * 16] = O_lo[dt][i] * inv_l;
      yh[dt * 16] = O_hi[dt][i] * inv_h;
    }
  }
}

extern "C" void kernel_launch(void* const* d_in, const int* in_sizes, int n_in,
                              void* d_out, int out_size, void* d_ws, size_t ws_size,
                              hipStream_t stream) {
  (void)in_sizes; (void)n_in; (void)out_size; (void)ws_size;
  const float* x    = (const float*)d_in[0];
  const float* Wq   = (const float*)d_in[1];
  const float* Wk   = (const float*)d_in[2];
  const float* Wv   = (const float*)d_in[3];
  const float* Wo   = (const float*)d_in[4];
  const float* cosb = (const float*)d_in[5];
  const float* sinb = (const float*)d_in[6];
  // d_in[7] = mask: unused (causal structure applied exactly)

  // workspace layout (~60 MB)
  float* q_ws = (float*)d_ws;                         // T*C fp32 (q, then y in-place)
  float* k_ws = q_ws + (size_t)T * C;                 // T*KVH*D fp32
  float* v_ws = k_ws + (size_t)T * KVH * D;           // T*KVH*D fp32
  __bf16* khi = (__bf16*)(v_ws + (size_t)T * KVH * D);          // 4 MB
  __bf16* klo = khi + (size_t)KVH * T * D;                      // 4 MB
  __bf16* vt  = klo + (size_t)KVH * T * D;                      // 4 MB

  float* out_y = (float*)d_out;
  float* out_k = out_y + (size_t)T * C;
  float* out_v = out_k + (size_t)KVH * T * D;

  dim3 blk(256);
  // projections: split-bf16 MFMA GEMMs
  gemm_split<<<dim3(C / 128, T / 128), blk, 0, stream>>>(x, Wq, q_ws, H * D, C);
  gemm_kv<<<dim3(16, T / 128), blk, 0, stream>>>(x, Wk, Wv, k_ws, v_ws, C);
  // rope on q and k (in place)
  int rope_total = T * (H + KVH) * (D / 2);
  rope_kernel<<<(rope_total + 255) / 256, blk, 0, stream>>>(q_ws, k_ws, cosb, sinb);
  // conversions + kv outputs
  convert_k<<<(KVH * T * D) / 256, blk, 0, stream>>>(k_ws, out_k, khi, klo);
  convert_v<<<dim3(T / 64, D / 64, KVH), blk, 0, stream>>>(v_ws, out_v, vt);
  // flash attention (balanced, LDS-staged; writes y over q_ws)
  flash_attn<<<dim3(16, H), blk, 0, stream>>>(q_ws, khi, klo, vt);
  // output projection
  gemm_split<<<dim3(C / 128, T / 128), blk, 0, stream>>>(q_ws, Wo, out_y, C, C);
}